// Round 1
// baseline (484.542 us; speedup 1.0000x reference)
//
#include <hip/hip_runtime.h>
#include <math.h>

// Fused Conv3d(3->16, k=3, valid) + bias + min over D + softmax over C.
// N=16, CIN=3, COUT=16, K=3, D=H=W=64 -> out [16,16,62,62] fp32.
//
// Strategy: depth-streaming direct conv. block = 256 = 16 co x 16 pixel
// strips (1x4 along w); tile = 8x8 output pixels per block. Each thread owns
// one output channel -> its 81 weights stay in VGPRs for the whole kernel.
// Ring of 3 accumulators per pixel handles the kd dimension as d streams;
// min over d' taken online; softmax via 16-lane shuffles (co = lane&15).

__global__ __launch_bounds__(256) void conv3d_min_softmax(
    const float* __restrict__ x,     // [16,3,64,64,64]
    const float* __restrict__ wgt,   // [16,3,3,3,3]
    const float* __restrict__ bias,  // [16]
    float* __restrict__ out)         // [16,16,62,62]
{
    const int tid = threadIdx.x;
    const int co  = tid & 15;        // output channel (lane bits 0..3)
    const int pix = tid >> 4;        // 0..15 pixel-strip id
    const int hh  = pix >> 1;        // 0..7 row within tile
    const int ww4 = (pix & 1) * 4;   // 0 or 4: strip start within tile
    const int n  = blockIdx.z;
    const int h0 = blockIdx.y * 8;
    const int w0 = blockIdx.x * 8;

    // x slice for current d: 3 ci x 10 rows x 10 cols (pad w to 12 for b128)
    __shared__ __align__(16) float sx[3][10][12];

    // per-thread weights: w[co][ci][kd][kh][kw], idx = ci*27 + kd*9 + kh*3 + kw
    float wreg[81];
#pragma unroll
    for (int i = 0; i < 81; ++i) wreg[i] = wgt[co * 81 + i];

    // ring accumulators: A0 completes this step (kd=2), A1 next (kd=1), A2 (kd=0)
    float A0[4], A1[4], A2[4], mv[4];
#pragma unroll
    for (int p = 0; p < 4; ++p) { A0[p] = A1[p] = A2[p] = 0.f; mv[p] = 1e30f; }

    const float* xn = x + (size_t)n * 3 * 64 * 64 * 64;

    for (int d = 0; d < 64; ++d) {
        // ---- stage 3x10x10 slice into LDS ----
        for (int idx = tid; idx < 300; idx += 256) {
            int ci  = idx / 100;
            int rem = idx - ci * 100;
            int r   = rem / 10;
            int c   = rem - r * 10;
            int gh  = min(h0 + r, 63);   // clamp: edge-tile halo, values unused
            int gw  = min(w0 + c, 63);
            sx[ci][r][c] = xn[((ci * 64 + d) * 64 + gh) * 64 + gw];
        }
        __syncthreads();

        // ---- accumulate: 3ci x 3kh x 3kw x 4p x 3kd = 324 FMA ----
#pragma unroll
        for (int ci = 0; ci < 3; ++ci) {
#pragma unroll
            for (int kh = 0; kh < 3; ++kh) {
                const float4 xa = *(const float4*)&sx[ci][hh + kh][ww4];
                const float4 xc = *(const float4*)&sx[ci][hh + kh][ww4 + 4];
                const float xr[8] = {xa.x, xa.y, xa.z, xa.w, xc.x, xc.y, xc.z, xc.w};
#pragma unroll
                for (int kw = 0; kw < 3; ++kw) {
                    const float wk0 = wreg[ci * 27 +  0 + kh * 3 + kw]; // kd=0
                    const float wk1 = wreg[ci * 27 +  9 + kh * 3 + kw]; // kd=1
                    const float wk2 = wreg[ci * 27 + 18 + kh * 3 + kw]; // kd=2
#pragma unroll
                    for (int p = 0; p < 4; ++p) {
                        const float xv = xr[p + kw];
                        A2[p] = fmaf(xv, wk0, A2[p]); // d' = d
                        A1[p] = fmaf(xv, wk1, A1[p]); // d' = d-1
                        A0[p] = fmaf(xv, wk2, A0[p]); // d' = d-2
                    }
                }
            }
        }

        // output d' = d-2 is now complete (d' in [0,61] iff d >= 2)
        if (d >= 2) {
#pragma unroll
            for (int p = 0; p < 4; ++p) mv[p] = fminf(mv[p], A0[p]);
        }
#pragma unroll
        for (int p = 0; p < 4; ++p) { A0[p] = A1[p]; A1[p] = A2[p]; A2[p] = 0.f; }
        __syncthreads();
    }

    // ---- epilogue: bias, softmax over 16 channels (lanes), store ----
    const float bv = bias[co];
    const int hp = h0 + hh;
#pragma unroll
    for (int p = 0; p < 4; ++p) {
        float v = mv[p] + bv;
        float mx = v;
#pragma unroll
        for (int off = 1; off < 16; off <<= 1)
            mx = fmaxf(mx, __shfl_xor(mx, off, 64));
        float e = __expf(v - mx);
        float s = e;
#pragma unroll
        for (int off = 1; off < 16; off <<= 1)
            s += __shfl_xor(s, off, 64);
        const int wp = w0 + ww4 + p;
        if (hp < 62 && wp < 62)
            out[(((size_t)n * 16 + co) * 62 + hp) * 62 + wp] = e / s;
    }
}

extern "C" void kernel_launch(void* const* d_in, const int* in_sizes, int n_in,
                              void* d_out, int out_size, void* d_ws, size_t ws_size,
                              hipStream_t stream) {
    const float* x    = (const float*)d_in[0];
    const float* wgt  = (const float*)d_in[1];
    const float* bias = (const float*)d_in[2];
    float* out        = (float*)d_out;
    dim3 grid(8, 8, 16);   // (w-tiles, h-tiles, n)
    dim3 block(256);
    hipLaunchKernelGGL(conv3d_min_softmax, grid, block, 0, stream,
                       x, wgt, bias, out);
}